// Round 10
// baseline (510.532 us; speedup 1.0000x reference)
//
#include <hip/hip_runtime.h>
#include <stdint.h>

typedef _Float16 half8 __attribute__((ext_vector_type(8)));
typedef float floatx4 __attribute__((ext_vector_type(4)));

__device__ __forceinline__ uint16_t f16bits(_Float16 h) {
  union { _Float16 f; uint16_t u; } x; x.f = h; return x.u;
}

// async global->LDS, 16B per lane; lds dst is wave-uniform base + lane*16
__device__ __forceinline__ void g2l16(const void* g, void* l) {
  __builtin_amdgcn_global_load_lds((const __attribute__((address_space(1))) void*)g,
                                   (__attribute__((address_space(3))) void*)l,
                                   16, 0, 0);
}

// ---------------- split fp32 -> f16 hi + f16 lo ----------------
__global__ __launch_bounds__(256) void split_f16_kernel(
    const float* __restrict__ x, uint16_t* __restrict__ hi,
    uint16_t* __restrict__ lo, int n4) {
  int i = blockIdx.x * 256 + threadIdx.x;
  if (i >= n4) return;
  float4 v = ((const float4*)x)[i];
  ushort4 h, l;
  _Float16 a;
  a = (_Float16)v.x; h.x = f16bits(a); l.x = f16bits((_Float16)(v.x - (float)a));
  a = (_Float16)v.y; h.y = f16bits(a); l.y = f16bits((_Float16)(v.y - (float)a));
  a = (_Float16)v.z; h.z = f16bits(a); l.z = f16bits((_Float16)(v.z - (float)a));
  a = (_Float16)v.w; h.w = f16bits(a); l.w = f16bits((_Float16)(v.w - (float)a));
  ((ushort4*)hi)[i] = h;
  ((ushort4*)lo)[i] = l;
}

// ---------------- fused H split + transpose ----------------
// H (b,t,e) f32 -> Hhi,Hlo (b,t,e) f16  AND  HT (b,e,t) f16(=hi)
__global__ __launch_bounds__(256) void split_h_kernel(
    const float* __restrict__ src, uint16_t* __restrict__ hi,
    uint16_t* __restrict__ lo, uint16_t* __restrict__ ht) {
  __shared__ uint16_t tile[64][65];
  const int e0 = blockIdx.x * 64;
  const int t0 = blockIdx.y * 64;
  const size_t bb = (size_t)blockIdx.z << 20;  // 1024*1024 per batch
  const int r = threadIdx.x >> 4;        // 0..15
  const int c = (threadIdx.x & 15) * 4;  // 0..60
#pragma unroll
  for (int it = 0; it < 4; ++it) {
    const int tr = r + it * 16;
    const size_t idx = bb + (size_t)(t0 + tr) * 1024 + e0 + c;
    float4 v = *(const float4*)(src + idx);
    ushort4 h, l;
    _Float16 a;
    a = (_Float16)v.x; h.x = f16bits(a); l.x = f16bits((_Float16)(v.x - (float)a));
    a = (_Float16)v.y; h.y = f16bits(a); l.y = f16bits((_Float16)(v.y - (float)a));
    a = (_Float16)v.z; h.z = f16bits(a); l.z = f16bits((_Float16)(v.z - (float)a));
    a = (_Float16)v.w; h.w = f16bits(a); l.w = f16bits((_Float16)(v.w - (float)a));
    *(ushort4*)(hi + idx) = h;
    *(ushort4*)(lo + idx) = l;
    tile[c + 0][tr] = h.x;
    tile[c + 1][tr] = h.y;
    tile[c + 2][tr] = h.z;
    tile[c + 3][tr] = h.w;
  }
  __syncthreads();
#pragma unroll
  for (int it = 0; it < 4; ++it) {
    const int er = r + it * 16;
    ushort4 o;
    o.x = tile[er][c + 0];
    o.y = tile[er][c + 1];
    o.z = tile[er][c + 2];
    o.w = tile[er][c + 3];
    *(ushort4*)(ht + bb + (size_t)(e0 + er) * 1024 + t0 + c) = o;
  }
}

// ------ C = A * B^T  (128x128 tile, BK=32, A-dbuf + B-single, 48KB) ------
// r5/r7 proven config (SQ_LDS_BANK_CONFLICT == 0).
// A:(M,K) row-major f16 (hi[,lo]), B:(N,K) row-major f16 (hi[,lo]).
// SPLIT: acc += Ahi*Blo + Ahi*Bhi + Alo*Bhi (bit-identical order to baseline)
// Schedule per K-step: stageB(kt) -> stageA(kt+1, other buf) -> ds_read fa
//   -> s_waitcnt vmcnt(4) [B landed, A(kt+1) in flight] -> s_barrier
//   -> passes (fbl, fbh, fal) -> __syncthreads.
// LDS swizzle: stored slot = chunk ^ key(row), key = (row&3)^(((row>>2)&1)<<1),
// via pre-swizzled GLOBAL source (LDS dst linear for g2l16).
template <bool SPLIT, int MODE, int GMAP>
__global__ __launch_bounds__(256, 4) void gemm_bt(
    const uint16_t* __restrict__ Ahi, const uint16_t* __restrict__ Alo,
    const uint16_t* __restrict__ Bhi, const uint16_t* __restrict__ Blo,
    uint16_t* __restrict__ Chi, uint16_t* __restrict__ Clo,
    float* __restrict__ Cf, const float* __restrict__ mask,
    const float* __restrict__ bias, int N, int K,
    long batchA, long batchB, long batchC) {
  constexpr int NBUF = SPLIT ? 2 : 1;
  constexpr int LOI = SPLIT ? 1 : 0;
  __shared__ __align__(16) uint16_t sA[2][NBUF][128 * 32];
  __shared__ __align__(16) uint16_t sB[NBUF][128 * 32];

  const int tid = threadIdx.x;
  const int lane = tid & 63;
  const int w = tid >> 6;            // wave 0..3
  const int wr = w >> 1, wc = w & 1; // 2x2 wave grid, 64x64 per wave
  const int quad = lane >> 4, l16 = lane & 15;

  int m_t, n_t, z;
  if constexpr (GMAP == 0) {
    m_t = blockIdx.x; n_t = blockIdx.y; z = 0;
  } else {
    z = blockIdx.x; m_t = blockIdx.y >> 3; n_t = blockIdx.y & 7;
  }
  const int m0 = m_t * 128;
  const int n0 = n_t * 128;
  const size_t zA = (size_t)z * batchA;
  const size_t zB = (size_t)z * batchB;
  const size_t zC = (size_t)z * batchC;

  const int r0 = w * 32 + (lane >> 2);  // row for q=0 chunk
  const int ldc =
      (((lane & 3) ^ ((lane >> 2) & 3) ^ (((lane >> 4) & 1) << 1)) * 16);

  const char* gAh0 = (const char*)(Ahi + zA + (size_t)(m0 + r0) * K) + ldc;
  const char* gAh1 = gAh0 + (size_t)16 * K * 2;
  const char* gBh0 = (const char*)(Bhi + zB + (size_t)(n0 + r0) * K) + ldc;
  const char* gBh1 = gBh0 + (size_t)16 * K * 2;
  const char* gAl0 = gAh0; const char* gAl1 = gAh1;
  const char* gBl0 = gBh0; const char* gBl1 = gBh1;
  if constexpr (SPLIT) {
    gAl0 = (const char*)(Alo + zA + (size_t)(m0 + r0) * K) + ldc;
    gAl1 = gAl0 + (size_t)16 * K * 2;
    gBl0 = (const char*)(Blo + zB + (size_t)(n0 + r0) * K) + ldc;
    gBl1 = gBl0 + (size_t)16 * K * 2;
  }

  auto stageA = [&](int buf, int kt) {
    const int kb = kt * 64;  // 32 f16 = 64B per row per K-tile
    g2l16(gAh0 + kb, &sA[buf][0][(w * 32) * 32]);
    g2l16(gAh1 + kb, &sA[buf][0][(w * 32 + 16) * 32]);
    if constexpr (SPLIT) {
      g2l16(gAl0 + kb, &sA[buf][LOI][(w * 32) * 32]);
      g2l16(gAl1 + kb, &sA[buf][LOI][(w * 32 + 16) * 32]);
    }
  };
  auto stageB = [&](int kt) {
    const int kb = kt * 64;
    g2l16(gBh0 + kb, &sB[0][(w * 32) * 32]);
    g2l16(gBh1 + kb, &sB[0][(w * 32 + 16) * 32]);
    if constexpr (SPLIT) {
      g2l16(gBl0 + kb, &sB[LOI][(w * 32) * 32]);
      g2l16(gBl1 + kb, &sB[LOI][(w * 32 + 16) * 32]);
    }
  };

  const int key = (l16 & 3) ^ (((l16 >> 2) & 1) << 1);
  const int aoff = (wr * 64 + l16) * 32 + ((quad ^ key) * 8);
  const int boff = (wc * 64 + l16) * 32 + ((quad ^ key) * 8);

  floatx4 acc[4][4];
  floatx4 zero = {0.f, 0.f, 0.f, 0.f};
#pragma unroll
  for (int i = 0; i < 4; ++i)
#pragma unroll
    for (int j = 0; j < 4; ++j) acc[i][j] = zero;

  const int nkt = K >> 5;
  stageA(0, 0);
  asm volatile("s_waitcnt vmcnt(0)" ::: "memory");
  __builtin_amdgcn_s_barrier();
  asm volatile("" ::: "memory");

  int cur = 0;
  for (int kt = 0; kt < nkt; ++kt) {
    stageB(kt);                                   // into single B buffer
    const bool pre = (kt + 1 < nkt);
    if (pre) stageA(cur ^ 1, kt + 1);             // prefetch next A (dbuf)

    half8 fa[4];
#pragma unroll
    for (int i = 0; i < 4; ++i) fa[i] = *(const half8*)&sA[cur][0][aoff + i * 512];

    if (pre) {
      if constexpr (SPLIT)
        asm volatile("s_waitcnt vmcnt(4)" ::: "memory");
      else
        asm volatile("s_waitcnt vmcnt(2)" ::: "memory");
    } else {
      asm volatile("s_waitcnt vmcnt(0)" ::: "memory");
    }
    __builtin_amdgcn_s_barrier();
    asm volatile("" ::: "memory");  // B reads must not hoist above barrier

    if constexpr (SPLIT) {
      half8 fbl[4];
#pragma unroll
      for (int j = 0; j < 4; ++j) fbl[j] = *(const half8*)&sB[1][boff + j * 512];
#pragma unroll
      for (int i = 0; i < 4; ++i)
#pragma unroll
        for (int j = 0; j < 4; ++j)
          acc[i][j] = __builtin_amdgcn_mfma_f32_16x16x32_f16(fa[i], fbl[j], acc[i][j], 0, 0, 0);
    }
    half8 fbh[4];
#pragma unroll
    for (int j = 0; j < 4; ++j) fbh[j] = *(const half8*)&sB[0][boff + j * 512];
#pragma unroll
    for (int i = 0; i < 4; ++i)
#pragma unroll
      for (int j = 0; j < 4; ++j)
        acc[i][j] = __builtin_amdgcn_mfma_f32_16x16x32_f16(fa[i], fbh[j], acc[i][j], 0, 0, 0);
    if constexpr (SPLIT) {
      half8 fal[4];
#pragma unroll
      for (int i = 0; i < 4; ++i) fal[i] = *(const half8*)&sA[cur][1][aoff + i * 512];
#pragma unroll
      for (int i = 0; i < 4; ++i)
#pragma unroll
        for (int j = 0; j < 4; ++j)
          acc[i][j] = __builtin_amdgcn_mfma_f32_16x16x32_f16(fal[i], fbh[j], acc[i][j], 0, 0, 0);
    }
    __syncthreads();
    cur ^= 1;
  }

  // epilogue: C/D layout col=lane&15, row=quad*4+r (m89/m91 verified)
  const int crow0 = m0 + wr * 64 + quad * 4;
  const int ccol0 = n0 + wc * 64 + l16;
#pragma unroll
  for (int j = 0; j < 4; ++j) {
    const int col = ccol0 + j * 16;
    float bj = 0.f;
    if constexpr (MODE == 0) bj = bias[col];
#pragma unroll
    for (int i = 0; i < 4; ++i) {
#pragma unroll
      for (int r = 0; r < 4; ++r) {
        const int row = crow0 + i * 16 + r;
        const size_t idx = zC + (size_t)row * N + col;
        float v = acc[i][j][r];
        if constexpr (MODE == 0) {
          v += bj;
          _Float16 h = (_Float16)v;
          Chi[idx] = f16bits(h);
          Clo[idx] = f16bits((_Float16)(v - (float)h));
        } else if constexpr (MODE == 1) {
          Cf[idx] = v + mask[idx];
        } else {
          Cf[idx] = v;
        }
      }
    }
  }
}

// ---- gemm1 fused: Pj(hi,lo) = S_f32 @ W^T + b  (A split fused in-kernel) ----
// Same 128x128/BK=32 schedule as gemm_bt<true,0,0>, but A is staged from the
// ORIGINAL f32 S: 4x global_load_dwordx4 -> regs (issued right after stageB,
// so vmcnt(4) still means "B's 4 g2l16 landed, A's 4 reg-loads in flight"),
// then split to hi/lo (bit-identical ops to split_f16_kernel) and
// ds_write_b64 into the SAME swizzled LDS layout after the MFMA passes.
// Eliminates the 128MB split_f16(S) round-trip.  B path unchanged (g2l16).
__global__ __launch_bounds__(256, 2) void gemm1_fused(
    const float* __restrict__ Af, const uint16_t* __restrict__ Bhi,
    const uint16_t* __restrict__ Blo, uint16_t* __restrict__ Chi,
    uint16_t* __restrict__ Clo, const float* __restrict__ bias,
    int N, int K) {
  __shared__ __align__(16) uint16_t sA[2][2][128 * 32];  // [dbuf][hi/lo]
  __shared__ __align__(16) uint16_t sB[2][128 * 32];     // [hi/lo] single

  const int tid = threadIdx.x;
  const int lane = tid & 63;
  const int w = tid >> 6;            // wave 0..3
  const int wr = w >> 1, wc = w & 1; // 2x2 wave grid, 64x64 per wave
  const int quad = lane >> 4, l16 = lane & 15;

  const int m0 = blockIdx.x * 128;
  const int n0 = blockIdx.y * 128;

  // B staging (g2l16, pre-swizzled global source; identical to gemm_bt)
  const int r0 = w * 32 + (lane >> 2);
  const int ldc =
      (((lane & 3) ^ ((lane >> 2) & 3) ^ (((lane >> 4) & 1) << 1)) * 16);
  const char* gBh0 = (const char*)(Bhi + (size_t)(n0 + r0) * K) + ldc;
  const char* gBh1 = gBh0 + (size_t)16 * K * 2;
  const char* gBl0 = (const char*)(Blo + (size_t)(n0 + r0) * K) + ldc;
  const char* gBl1 = gBl0 + (size_t)16 * K * 2;
  auto stageB = [&](int kt) {
    const int kb = kt * 64;
    g2l16(gBh0 + kb, &sB[0][(w * 32) * 32]);
    g2l16(gBh1 + kb, &sB[0][(w * 32 + 16) * 32]);
    g2l16(gBl0 + kb, &sB[1][(w * 32) * 32]);
    g2l16(gBl1 + kb, &sB[1][(w * 32 + 16) * 32]);
  };

  // A staging (reg-staged f32 -> split -> swizzled ds_write):
  // lane l: row_rel = w*32 + (l>>3) + 8*it, f32 16B-chunk c32 = l&7.
  // f16 16B-chunk = c32>>1, stored slot = (c32>>1) ^ key(row),
  // key(row) = (row&3)^(((row>>2)&1)<<1); row&7 == l>>3 (w*32, 8*it ≡ 0 mod 8)
  const int ra8 = lane >> 3;  // 0..7
  const int c32 = lane & 7;
  const int keyA = (ra8 & 3) ^ (((ra8 >> 2) & 1) << 1);
  const int wsl = ((c32 >> 1) ^ keyA) * 8 + (c32 & 1) * 4;  // elem off in row
  const float* gA = Af + (size_t)(m0 + w * 32 + ra8) * K + c32 * 4;

  float4 av[4];
  auto issueA = [&](int kt) {
#pragma unroll
    for (int it = 0; it < 4; ++it)
      av[it] = *(const float4*)(gA + (size_t)it * 8 * K + kt * 32);
  };
  auto writeA = [&](int buf) {
#pragma unroll
    for (int it = 0; it < 4; ++it) {
      ushort4 hh, ll;
      _Float16 a;
      a = (_Float16)av[it].x; hh.x = f16bits(a); ll.x = f16bits((_Float16)(av[it].x - (float)a));
      a = (_Float16)av[it].y; hh.y = f16bits(a); ll.y = f16bits((_Float16)(av[it].y - (float)a));
      a = (_Float16)av[it].z; hh.z = f16bits(a); ll.z = f16bits((_Float16)(av[it].z - (float)a));
      a = (_Float16)av[it].w; hh.w = f16bits(a); ll.w = f16bits((_Float16)(av[it].w - (float)a));
      const int off = (w * 32 + ra8 + 8 * it) * 32 + wsl;
      *(ushort4*)&sA[buf][0][off] = hh;
      *(ushort4*)&sA[buf][1][off] = ll;
    }
  };

  // compute-phase offsets (identical to gemm_bt)
  const int key = (l16 & 3) ^ (((l16 >> 2) & 1) << 1);
  const int aoff = (wr * 64 + l16) * 32 + ((quad ^ key) * 8);
  const int boff = (wc * 64 + l16) * 32 + ((quad ^ key) * 8);

  floatx4 acc[4][4];
  floatx4 zero = {0.f, 0.f, 0.f, 0.f};
#pragma unroll
  for (int i = 0; i < 4; ++i)
#pragma unroll
    for (int j = 0; j < 4; ++j) acc[i][j] = zero;

  const int nkt = K >> 5;
  // prologue: A(0) -> regs -> split -> LDS buf0
  issueA(0);
  writeA(0);  // compiler inserts the vmcnt wait before av use
  __syncthreads();

  int cur = 0;
  for (int kt = 0; kt < nkt; ++kt) {
    stageB(kt);                        // 4x g2l16 (oldest in vmcnt queue)
    asm volatile("" ::: "memory");     // keep A reg-loads AFTER stageB
    const bool pre = (kt + 1 < nkt);
    if (pre) issueA(kt + 1);           // 4x global_load_dwordx4 -> av

    half8 fa[4];
#pragma unroll
    for (int i = 0; i < 4; ++i) fa[i] = *(const half8*)&sA[cur][0][aoff + i * 512];

    // B's 4 loads done; A's 4 reg-loads may stay in flight
    if (pre) asm volatile("s_waitcnt vmcnt(4)" ::: "memory");
    else     asm volatile("s_waitcnt vmcnt(0)" ::: "memory");
    __builtin_amdgcn_s_barrier();
    asm volatile("" ::: "memory");  // B reads must not hoist above barrier

    {  // pass 1: Ahi * Blo
      half8 fbl[4];
#pragma unroll
      for (int j = 0; j < 4; ++j) fbl[j] = *(const half8*)&sB[1][boff + j * 512];
#pragma unroll
      for (int i = 0; i < 4; ++i)
#pragma unroll
        for (int j = 0; j < 4; ++j)
          acc[i][j] = __builtin_amdgcn_mfma_f32_16x16x32_f16(fa[i], fbl[j], acc[i][j], 0, 0, 0);
    }
    half8 fbh[4];  // pass 2: Ahi * Bhi
#pragma unroll
    for (int j = 0; j < 4; ++j) fbh[j] = *(const half8*)&sB[0][boff + j * 512];
#pragma unroll
    for (int i = 0; i < 4; ++i)
#pragma unroll
      for (int j = 0; j < 4; ++j)
        acc[i][j] = __builtin_amdgcn_mfma_f32_16x16x32_f16(fa[i], fbh[j], acc[i][j], 0, 0, 0);
    {  // pass 3: Alo * Bhi
      half8 fal[4];
#pragma unroll
      for (int i = 0; i < 4; ++i) fal[i] = *(const half8*)&sA[cur][1][aoff + i * 512];
#pragma unroll
      for (int i = 0; i < 4; ++i)
#pragma unroll
        for (int j = 0; j < 4; ++j)
          acc[i][j] = __builtin_amdgcn_mfma_f32_16x16x32_f16(fal[i], fbh[j], acc[i][j], 0, 0, 0);
    }
    // split+write next A tile into the other buffer (no one reads it yet);
    // end-of-step __syncthreads makes the writes visible for the next step
    if (pre) writeA(cur ^ 1);
    __syncthreads();
    cur ^= 1;
  }

  // epilogue: MODE 0 (split f16 + bias), C/D layout col=lane&15, row=quad*4+r
  const int crow0 = m0 + wr * 64 + quad * 4;
  const int ccol0 = n0 + wc * 64 + l16;
#pragma unroll
  for (int j = 0; j < 4; ++j) {
    const int col = ccol0 + j * 16;
    const float bj = bias[col];
#pragma unroll
    for (int i = 0; i < 4; ++i) {
#pragma unroll
      for (int r = 0; r < 4; ++r) {
        const int row = crow0 + i * 16 + r;
        const size_t idx = (size_t)row * N + col;
        float v = acc[i][j][r] + bj;
        _Float16 h = (_Float16)v;
        Chi[idx] = f16bits(h);
        Clo[idx] = f16bits((_Float16)(v - (float)h));
      }
    }
  }
}

// ---------------- row softmax: fp32 scores -> f16 probs ----------------
__global__ __launch_bounds__(256) void softmax_kernel(
    const float* __restrict__ sc, uint16_t* __restrict__ p) {
  const int row = blockIdx.x;
  const float* x = sc + (size_t)row * 1024;
  const int t = threadIdx.x;
  float4 v = ((const float4*)x)[t];
  float m = fmaxf(fmaxf(v.x, v.y), fmaxf(v.z, v.w));
#pragma unroll
  for (int off = 32; off; off >>= 1) m = fmaxf(m, __shfl_xor(m, off));
  __shared__ float redm[4];
  __shared__ float reds[4];
  const int wv = t >> 6, ln = t & 63;
  if (ln == 0) redm[wv] = m;
  __syncthreads();
  m = fmaxf(fmaxf(redm[0], redm[1]), fmaxf(redm[2], redm[3]));
  float e0 = __expf(v.x - m), e1 = __expf(v.y - m);
  float e2 = __expf(v.z - m), e3 = __expf(v.w - m);
  float s = e0 + e1 + e2 + e3;
#pragma unroll
  for (int off = 32; off; off >>= 1) s += __shfl_xor(s, off);
  if (ln == 0) reds[wv] = s;
  __syncthreads();
  s = reds[0] + reds[1] + reds[2] + reds[3];
  float inv = 1.f / s;
  ushort4 o;
  o.x = f16bits((_Float16)(e0 * inv));
  o.y = f16bits((_Float16)(e1 * inv));
  o.z = f16bits((_Float16)(e2 * inv));
  o.w = f16bits((_Float16)(e3 * inv));
  ((ushort4*)(p + (size_t)row * 1024))[t] = o;
}

// ---------------- H (b,t,e) f32 -> H_T (b,e,t) f16 (fallback path) --------
__global__ __launch_bounds__(256) void transpose_f16_kernel(
    const float* __restrict__ src, uint16_t* __restrict__ dst) {
  __shared__ uint16_t tile[64][65];
  const int e0 = blockIdx.x * 64;
  const int t0 = blockIdx.y * 64;
  const size_t bb = (size_t)blockIdx.z << 20;
  const int r = threadIdx.x >> 4;
  const int c = (threadIdx.x & 15) * 4;
#pragma unroll
  for (int it = 0; it < 4; ++it) {
    const int tr = r + it * 16;
    float4 v = *(const float4*)(src + bb + (size_t)(t0 + tr) * 1024 + e0 + c);
    tile[c + 0][tr] = f16bits((_Float16)v.x);
    tile[c + 1][tr] = f16bits((_Float16)v.y);
    tile[c + 2][tr] = f16bits((_Float16)v.z);
    tile[c + 3][tr] = f16bits((_Float16)v.w);
  }
  __syncthreads();
#pragma unroll
  for (int it = 0; it < 4; ++it) {
    const int er = r + it * 16;
    ushort4 o;
    o.x = tile[er][c + 0];
    o.y = tile[er][c + 1];
    o.z = tile[er][c + 2];
    o.w = tile[er][c + 3];
    *(ushort4*)(dst + bb + (size_t)(e0 + er) * 1024 + t0 + c) = o;
  }
}

extern "C" void kernel_launch(void* const* d_in, const int* in_sizes, int n_in,
                              void* d_out, int out_size, void* d_ws, size_t ws_size,
                              hipStream_t stream) {
  (void)in_sizes; (void)n_in; (void)out_size;
  const float* S    = (const float*)d_in[0];  // (16,1024,1024)
  const float* H    = (const float*)d_in[1];  // (16,1024,1024)
  const float* mask = (const float*)d_in[2];  // (16,1024,1024)
  const float* Ww   = (const float*)d_in[3];  // (1024,1024)
  const float* Wb   = (const float*)d_in[4];  // (1024,)
  float* out = (float*)d_out;
  char* ws = (char*)d_ws;
  const size_t MB = 1024ull * 1024ull;

  // workspace layout:
  uint16_t* Whi  = (uint16_t*)(ws + 0 * MB);    // 2MB
  uint16_t* Wlo  = (uint16_t*)(ws + 2 * MB);    // 2MB
  uint16_t* Pjhi = (uint16_t*)(ws + 4 * MB);    // 32MB  projection hi
  uint16_t* Pjlo = (uint16_t*)(ws + 36 * MB);   // 32MB  projection lo
  uint16_t* Hhi  = (uint16_t*)(ws + 68 * MB);   // 32MB
  uint16_t* Hlo  = (uint16_t*)(ws + 100 * MB);  // 32MB
  float*    SC   = (float*)(ws + 132 * MB);     // 64MB scores
  uint16_t* PR   = (uint16_t*)(ws + 68 * MB);   // 32MB probs, aliases Hhi

  const bool roomy = ws_size >= 229ull * MB;
  uint16_t* HT = roomy ? (uint16_t*)(ws + 196 * MB)   // 32MB dedicated
                       : (uint16_t*)(ws + 100 * MB);  // aliases Hlo (late write)

  // split W into f16 hi/lo (S split is fused into gemm1 now)
  split_f16_kernel<<<1024, 256, 0, stream>>>(Ww, Whi, Wlo, 256 * 1024);
  if (roomy) {
    split_h_kernel<<<dim3(16, 16, 16), 256, 0, stream>>>(H, Hhi, Hlo, HT);
  } else {
    split_f16_kernel<<<16384, 256, 0, stream>>>(H, Hhi, Hlo, 4 * 1024 * 1024);
  }

  // S_ = S @ W^T + b   (fused f32->hi/lo A-staging; GMAP0-style grid)
  gemm1_fused<<<dim3(128, 8, 1), 256, 0, stream>>>(
      S, Whi, Wlo, Pjhi, Pjlo, Wb, 1024, 1024);
  // scores = S_ @ H^T + mask  (GMAP 1: x = batch so lin%8 partitions batches)
  gemm_bt<true, 1, 1><<<dim3(16, 64, 1), 256, 0, stream>>>(
      Pjhi, Pjlo, Hhi, Hlo, nullptr, nullptr, SC, mask, nullptr,
      1024, 1024, 1048576, 1048576, 1048576);
  // P = softmax(scores) rowwise -> f16
  softmax_kernel<<<16384, 256, 0, stream>>>(SC, PR);
  if (!roomy) {
    transpose_f16_kernel<<<dim3(16, 16, 16), 256, 0, stream>>>(H, HT);
  }
  // out = P @ H  ==  P @ (H_T)^T  (r7-proven BK=32 kernel)
  gemm_bt<false, 2, 1><<<dim3(16, 64, 1), 256, 0, stream>>>(
      PR, nullptr, HT, nullptr, nullptr, nullptr, out, nullptr, nullptr,
      1024, 1024, 1048576, 1048576, 1048576);
}